// Round 12
// baseline (309.141 us; speedup 1.0000x reference)
//
#include <hip/hip_runtime.h>

// ---------------------------------------------------------------------------
// RGAT 2-hop, N=100000, E=1600000, D=64, R=64.
// R12 = R11 + XCD-partitioned CSR build: blockIdx%8 = class ~ XCD
// (round-robin dispatch). Class x only handles edges with head in its N/8
// range, so each csr 64B line is dirtied by ONE XCD's L2 (3.2 MB region
// fits 4 MB L2), accumulating all stores before a single writeback --
// R11's 96 MB write amplification (8 XCDs flushing partial lines) -> ~26 MB.
// Cost: each class scans the whole edge list (LLC-resident, cheap reads;
// tail/etype predicated on range match). DEGSTRIDE=16 (stride proven
// irrelevant R9 vs R11; halves memset). proj+cast fused into one launch.
// Hop unchanged (R10/R11): 16-lane groups, 4 nodes/wave, lane=dim-quad,
// U,V bf16 ushort8 in LDS, DPP row_ror dot, 8-edge fast path + gated tail.
// ---------------------------------------------------------------------------

#define NEG_SLOPE 0.2f
#define CAP 64
#define DEGSTRIDE 16  // ints => 64 B per counter
#define NCLS 8        // XCD classes

__device__ __forceinline__ float b2f_lo(unsigned x) {
    return __uint_as_float(x << 16);
}
__device__ __forceinline__ float b2f_hi(unsigned x) {
    return __uint_as_float(x & 0xffff0000u);
}
__device__ __forceinline__ unsigned short f2b(float x) {  // RNE
    unsigned u = __float_as_uint(x);
    unsigned r = u + 0x7fffu + ((u >> 16) & 1u);
    return (unsigned short)(r >> 16);
}

// sum over the 16 lanes of a row-group; result in ALL 16 lanes. VALU pipe.
__device__ __forceinline__ float ror_sum16(float x) {
#define ROR_ADD(ctrl)                                                          \
    x += __int_as_float(                                                       \
        __builtin_amdgcn_update_dpp(0, __float_as_int(x), ctrl, 0xf, 0xf, true))
    ROR_ADD(0x121);  // row_ror:1
    ROR_ADD(0x122);  // row_ror:2
    ROR_ADD(0x124);  // row_ror:4
    ROR_ADD(0x128);  // row_ror:8
#undef ROR_ADD
    return x;
}

// Fused init: blocks [0,R) do Wuv projection; the rest cast ent -> bf16.
// Wuvb packed bf16: per (r, dim-quad s): 8 ushorts [U0..U3 | V0..V3].
__global__ __launch_bounds__(256) void init_kernel(
    const float* __restrict__ W, const float* __restrict__ rel,
    unsigned short* __restrict__ Wuvb, const float* __restrict__ ent,
    unsigned short* __restrict__ entb, int n4, int R) {
    if ((int)blockIdx.x < R) {
        int r = blockIdx.x;
        int i = threadIdx.x;  // use 128 of 256
        __shared__ float rels[64];
        if (i < 64) rels[i] = rel[r * 64 + i];
        __syncthreads();
        if (i < 128) {
            float s = 0.f;
#pragma unroll
            for (int j = 0; j < 64; ++j) s += W[i * 64 + j] * rels[j];
            int d = i & 63, half = i >> 6;
            Wuvb[r * 128 + (d >> 2) * 8 + half * 4 + (d & 3)] = f2b(s);
        }
    } else {
        int i = (blockIdx.x - R) * 256 + threadIdx.x;
        if (i < n4) {
            float4 v = *(const float4*)(ent + (long)i * 4);
            ushort4 o = {f2b(v.x), f2b(v.y), f2b(v.z), f2b(v.w)};
            *(ushort4*)(entb + (long)i * 4) = o;
        }
    }
}

// ---------------- XCD-partitioned one-pass CSR build ----------------
// class = blockIdx % 8 (~XCD via round-robin dispatch); each class scans
// all edges, keeps those with head in its node range. Locality heuristic
// only -- correct under any block->XCD mapping.
__global__ __launch_bounds__(256) void build_kernel(
    const int* __restrict__ head, const int* __restrict__ tail,
    const int* __restrict__ etype, int* __restrict__ deg,
    int* __restrict__ csr, int E, int N) {
    int cls = blockIdx.x & (NCLS - 1);
    int chunk = blockIdx.x / NCLS;
    int nchunks = gridDim.x / NCLS;
    int range = (N + NCLS - 1) / NCLS;
    int lo = cls * range;
    int hi = min(N, lo + range);
    long e0 = (long)chunk * E / nchunks;
    long e1 = (long)(chunk + 1) * E / nchunks;
    for (long i = e0 + threadIdx.x; i < e1; i += 256) {
        int h = head[i];
        if (h >= lo && h < hi) {
            int entry = (tail[i] << 6) | etype[i];
            int c = atomicAdd(deg + (long)h * DEGSTRIDE, 1);
            if (c < CAP) csr[(long)h * CAP + c] = entry;
        }
    }
}

// ---------------- fused hop (16-lane groups) ----------------
// 512 threads = 8 waves = 32 nodes per block. Group = 16 lanes = 1 node,
// lane s owns dims 4s..4s+3.
__global__ __launch_bounds__(512) void hop_kernel(
    const int* __restrict__ deg16, const int* __restrict__ csr,
    const unsigned short* __restrict__ Wuvb,
    const unsigned short* __restrict__ embb, const float* res_prev,
    unsigned short* embb_out, float* res_out, int N) {
    __shared__ unsigned short sUV[64 * 136];  // 17 KB, skewed stride
    for (int k = threadIdx.x; k < 64 * 128; k += 512) {
        int r = k >> 7, q = k & 127;
        sUV[r * 136 + q] = Wuvb[k];
    }
    __syncthreads();

    int tid = threadIdx.x;
    int s = tid & 15;
    int node = blockIdx.x * 32 + (tid >> 4);
    bool valid = node < N;
    long nb64 = (long)node * 64;

    uint2 hdp = valid ? *(const uint2*)(embb + nb64 + s * 4)
                      : make_uint2(0u, 0u);
    float hd0 = b2f_lo(hdp.x), hd1 = b2f_hi(hdp.x);
    float hd2 = b2f_lo(hdp.y), hd3 = b2f_hi(hdp.y);

    int deg = valid ? min(deg16[(long)node * DEGSTRIDE], CAP) : 0;
    int r0 = node * CAP;
    // wave-uniform min/max degree over the wave's 4 groups
    int dmin = min(min(__shfl(deg, 0), __shfl(deg, 16)),
                   min(__shfl(deg, 32), __shfl(deg, 48)));
    int dmax = max(max(__shfl(deg, 0), __shfl(deg, 16)),
                   max(__shfl(deg, 32), __shfl(deg, 48)));

    float a0 = 0.f, a1 = 0.f, a2 = 0.f, a3 = 0.f, l = 0.f;

    auto edge_body = [&](int pe, uint2 rw, bool gated, int idx) {
        int rr = pe & 63;
        uint4 uv = *(const uint4*)(sUV + rr * 136 + s * 8);
        float U0 = b2f_lo(uv.x), U1 = b2f_hi(uv.x);
        float U2 = b2f_lo(uv.y), U3 = b2f_hi(uv.y);
        float V0 = b2f_lo(uv.z), V1 = b2f_hi(uv.z);
        float V2 = b2f_lo(uv.w), V3 = b2f_hi(uv.w);
        float e0 = b2f_lo(rw.x), e1 = b2f_hi(rw.x);
        float e2 = b2f_lo(rw.y), e3 = b2f_hi(rw.y);
        float sd = hd0 * U0 + hd1 * U1 + hd2 * U2 + hd3 * U3 +
                   e0 * V0 + e1 * V1 + e2 * V2 + e3 * V3;
        sd = ror_sum16(sd);                   // 64-dot in all 16 lanes
        float p = fmaxf(sd, NEG_SLOPE * sd);  // leaky (slope<1)
        float w = __expf(p);
        if (gated) w = (idx < deg) ? w : 0.f;
        l += w;
        a0 += w * e0; a1 += w * e1; a2 += w * e2; a3 += w * e3;
    };

    int c = 0;
    // fast path: 8 edges/iter, all groups full, no gating
    for (; c + 8 <= dmin; c += 8) {
        uint4 ea = *(const uint4*)(csr + r0 + c);
        uint4 eb = *(const uint4*)(csr + r0 + c + 4);
        int pe[8] = {(int)ea.x, (int)ea.y, (int)ea.z, (int)ea.w,
                     (int)eb.x, (int)eb.y, (int)eb.z, (int)eb.w};
        uint2 rw[8];
#pragma unroll
        for (int u = 0; u < 8; ++u)
            rw[u] = *(const uint2*)(embb + (long)(pe[u] >> 6) * 64 + s * 4);
#pragma unroll
        for (int u = 0; u < 8; ++u) edge_body(pe[u], rw[u], false, 0);
    }
    // gated tail: 4 edges/iter; pe forced 0 before gather (poison safety)
    for (; c < dmax; c += 4) {
        uint4 e4 = *(const uint4*)(csr + r0 + c);
        int pe[4];
        pe[0] = (c + 0 < deg) ? (int)e4.x : 0;
        pe[1] = (c + 1 < deg) ? (int)e4.y : 0;
        pe[2] = (c + 2 < deg) ? (int)e4.z : 0;
        pe[3] = (c + 3 < deg) ? (int)e4.w : 0;
        uint2 rw[4];
#pragma unroll
        for (int u = 0; u < 4; ++u)
            rw[u] = *(const uint2*)(embb + (long)(pe[u] >> 6) * 64 + s * 4);
#pragma unroll
        for (int u = 0; u < 4; ++u) edge_body(pe[u], rw[u], true, c + u);
    }

    if (valid) {
        float inv = (l > 0.f) ? 1.f / l : 0.f;
        float v0 = hd0 + a0 * inv, v1 = hd1 + a1 * inv;
        float v2 = hd2 + a2 * inv, v3 = hd3 + a3 * inv;
        float sq = v0 * v0 + v1 * v1 + v2 * v2 + v3 * v3;
        sq = ror_sum16(sq);                       // group-uniform
        float rn = 1.f / fmaxf(sqrtf(sq), 1e-12f);
        v0 *= rn; v1 *= rn; v2 *= rn; v3 *= rn;
        if (embb_out) {
            ushort4 o = {f2b(v0), f2b(v1), f2b(v2), f2b(v3)};
            *(ushort4*)(embb_out + nb64 + s * 4) = o;
        }
        float4 rp = *(const float4*)(res_prev + nb64 + s * 4);
        float4 ro = {0.5f * rp.x + v0, 0.5f * rp.y + v1,
                     0.5f * rp.z + v2, 0.5f * rp.w + v3};
        *(float4*)(res_out + nb64 + s * 4) = ro;
    }
}

extern "C" void kernel_launch(void* const* d_in, const int* in_sizes, int n_in,
                              void* d_out, int out_size, void* d_ws, size_t ws_size,
                              hipStream_t stream) {
    const int*   edge_index = (const int*)d_in[0];   // [2, E]
    const int*   etype      = (const int*)d_in[1];   // [E]
    const float* ent        = (const float*)d_in[2]; // [N, 64]
    const float* rel        = (const float*)d_in[3]; // [R, 64]
    const float* W          = (const float*)d_in[4]; // [128, 64]

    const int E = in_sizes[1];
    const int N = in_sizes[2] / 64;
    const int R = in_sizes[3] / 64;
    const int* head = edge_index;
    const int* tail = edge_index + E;
    float* out = (float*)d_out;

    // workspace layout
    char* w = (char*)d_ws;
    unsigned short* Wuvb = (unsigned short*)w;  w += (size_t)R * 128 * 2;
    int* deg = (int*)w;                         w += (size_t)N * DEGSTRIDE * 4;
    int* csr = (int*)w;                         w += (size_t)N * CAP * 4;
    unsigned short* entb = (unsigned short*)w;  w += (size_t)N * 64 * 2;
    unsigned short* emb1b = (unsigned short*)w; w += (size_t)N * 64 * 2;

    const int n4 = N * 16;                      // float4s to cast
    const int ib = R + (n4 + 255) / 256;
    const int hb = (N + 31) / 32;
    const int bb = 2048;                        // 8 classes x 256 chunks

    init_kernel<<<ib, 256, 0, stream>>>(W, rel, Wuvb, ent, entb, n4, R);

    // XCD-partitioned CSR build (graph constant across hops)
    hipMemsetAsync(deg, 0, (size_t)N * DEGSTRIDE * 4, stream);
    build_kernel<<<bb, 256, 0, stream>>>(head, tail, etype, deg, csr, E, N);

    // hop 1
    hop_kernel<<<hb, 512, 0, stream>>>(deg, csr, Wuvb, entb, ent, emb1b, out, N);
    // hop 2 (res in place)
    hop_kernel<<<hb, 512, 0, stream>>>(deg, csr, Wuvb, emb1b, out, nullptr, out, N);
}

// Round 13
// 271.674 us; speedup vs baseline: 1.1379x; 1.1379x over previous
//
#include <hip/hip_runtime.h>

// ---------------------------------------------------------------------------
// RGAT 2-hop, N=100000, E=1600000, D=64, R=64.
// R13: two-phase binned CSR build (fixes the 83-96 MB write amplification
// that survived R9-R12: scattered 4B stores to a line arrive spread over
// the whole kernel from all XCDs, so L2 evicts partial lines each time).
// Phase A: partition edges into 196 node-range buckets ((h>>9)); LDS
// histogram + one global-cursor atomic per (block,bucket) + rescan; writes
// are ~128B single-writer runs into per-bucket streams. Phase B: one block
// per bucket scatters its contiguous stream into its PRIVATE 131KB csr
// region within ~10us -> lines accumulate fully, write once; deg written
// packed+coalesced from LDS (memset + DEGSTRIDE padding deleted).
// Hop unchanged (R10-R12): 16-lane groups, 4 nodes/wave, lane=dim-quad,
// U,V bf16 ushort8 LDS, DPP row_ror dot, 8-edge fast path + gated tail.
// ---------------------------------------------------------------------------

#define NEG_SLOPE 0.2f
#define CAP 64
#define BKT_SHIFT 9                  // 512 nodes per bucket
#define BKT_CAP 16384                // stream slots per bucket (avg ~8163)

__device__ __forceinline__ float b2f_lo(unsigned x) {
    return __uint_as_float(x << 16);
}
__device__ __forceinline__ float b2f_hi(unsigned x) {
    return __uint_as_float(x & 0xffff0000u);
}
__device__ __forceinline__ unsigned short f2b(float x) {  // RNE
    unsigned u = __float_as_uint(x);
    unsigned r = u + 0x7fffu + ((u >> 16) & 1u);
    return (unsigned short)(r >> 16);
}

// sum over the 16 lanes of a row-group; result in ALL 16 lanes. VALU pipe.
__device__ __forceinline__ float ror_sum16(float x) {
#define ROR_ADD(ctrl)                                                          \
    x += __int_as_float(                                                       \
        __builtin_amdgcn_update_dpp(0, __float_as_int(x), ctrl, 0xf, 0xf, true))
    ROR_ADD(0x121);  // row_ror:1
    ROR_ADD(0x122);  // row_ror:2
    ROR_ADD(0x124);  // row_ror:4
    ROR_ADD(0x128);  // row_ror:8
#undef ROR_ADD
    return x;
}

// Fused init: blocks [0,R): Wuv projection; block R: zero bucket cursors;
// rest: cast ent -> bf16.
__global__ __launch_bounds__(256) void init_kernel(
    const float* __restrict__ W, const float* __restrict__ rel,
    unsigned short* __restrict__ Wuvb, const float* __restrict__ ent,
    unsigned short* __restrict__ entb, int* __restrict__ gcursor,
    int n4, int R, int nbkt) {
    if ((int)blockIdx.x < R) {
        int r = blockIdx.x;
        int i = threadIdx.x;  // use 128 of 256
        __shared__ float rels[64];
        if (i < 64) rels[i] = rel[r * 64 + i];
        __syncthreads();
        if (i < 128) {
            float s = 0.f;
#pragma unroll
            for (int j = 0; j < 64; ++j) s += W[i * 64 + j] * rels[j];
            int d = i & 63, half = i >> 6;
            Wuvb[r * 128 + (d >> 2) * 8 + half * 4 + (d & 3)] = f2b(s);
        }
    } else if ((int)blockIdx.x == R) {
        if ((int)threadIdx.x < nbkt) gcursor[threadIdx.x] = 0;
    } else {
        int i = (blockIdx.x - R - 1) * 256 + threadIdx.x;
        if (i < n4) {
            float4 v = *(const float4*)(ent + (long)i * 4);
            ushort4 o = {f2b(v.x), f2b(v.y), f2b(v.z), f2b(v.w)};
            *(ushort4*)(entb + (long)i * 4) = o;
        }
    }
}

// ---------------- Phase A: partition edges into bucket streams ----------
__global__ __launch_bounds__(256) void binA_kernel(
    const int* __restrict__ head, const int* __restrict__ tail,
    const int* __restrict__ etype, int* __restrict__ gcursor,
    uint2* __restrict__ stream, int E, int nbkt) {
    __shared__ int lcnt[256];
    __shared__ int lbase[256];
    int nb = gridDim.x;
    long e0 = (long)blockIdx.x * E / nb;
    long e1 = (long)(blockIdx.x + 1) * E / nb;
    for (int i = threadIdx.x; i < nbkt; i += 256) lcnt[i] = 0;
    __syncthreads();
    for (long i = e0 + threadIdx.x; i < e1; i += 256)
        atomicAdd(&lcnt[head[i] >> BKT_SHIFT], 1);
    __syncthreads();
    for (int b = threadIdx.x; b < nbkt; b += 256) {
        lbase[b] = atomicAdd(gcursor + b, lcnt[b]);
        lcnt[b] = 0;
    }
    __syncthreads();
    for (long i = e0 + threadIdx.x; i < e1; i += 256) {
        int h = head[i];
        int b = h >> BKT_SHIFT;
        int entry = (tail[i] << 6) | etype[i];
        int p = lbase[b] + atomicAdd(&lcnt[b], 1);
        if (p < BKT_CAP)
            stream[(long)b * BKT_CAP + p] = make_uint2((unsigned)h, (unsigned)entry);
    }
}

// ---------------- Phase B: per-bucket local CSR build -------------------
// One block per bucket; csr region (<=131 KB) is block-private and L2-hot.
__global__ __launch_bounds__(256) void binB_kernel(
    const int* __restrict__ gcursor, const uint2* __restrict__ stream,
    int* __restrict__ deg, int* __restrict__ csr, int N) {
    __shared__ int cnt[512];
    int b = blockIdx.x;
    for (int i = threadIdx.x; i < 512; i += 256) cnt[i] = 0;
    __syncthreads();
    int n = min(gcursor[b], BKT_CAP);
    const uint2* sp = stream + (long)b * BKT_CAP;
    for (int i = threadIdx.x; i < n; i += 256) {
        uint2 e = sp[i];
        int c = atomicAdd(&cnt[e.x & 511], 1);
        if (c < CAP) csr[(long)e.x * CAP + c] = (int)e.y;
    }
    __syncthreads();
    int nodebase = b << BKT_SHIFT;
    for (int i = threadIdx.x; i < 512; i += 256) {
        int node = nodebase + i;
        if (node < N) deg[node] = cnt[i];
    }
}

// ---------------- fused hop (16-lane groups) ----------------
// 512 threads = 8 waves = 32 nodes per block. Group = 16 lanes = 1 node,
// lane s owns dims 4s..4s+3.
__global__ __launch_bounds__(512) void hop_kernel(
    const int* __restrict__ degp, const int* __restrict__ csr,
    const unsigned short* __restrict__ Wuvb,
    const unsigned short* __restrict__ embb, const float* res_prev,
    unsigned short* embb_out, float* res_out, int N) {
    __shared__ unsigned short sUV[64 * 136];  // 17 KB, skewed stride
    for (int k = threadIdx.x; k < 64 * 128; k += 512) {
        int r = k >> 7, q = k & 127;
        sUV[r * 136 + q] = Wuvb[k];
    }
    __syncthreads();

    int tid = threadIdx.x;
    int s = tid & 15;
    int node = blockIdx.x * 32 + (tid >> 4);
    bool valid = node < N;
    long nb64 = (long)node * 64;

    uint2 hdp = valid ? *(const uint2*)(embb + nb64 + s * 4)
                      : make_uint2(0u, 0u);
    float hd0 = b2f_lo(hdp.x), hd1 = b2f_hi(hdp.x);
    float hd2 = b2f_lo(hdp.y), hd3 = b2f_hi(hdp.y);

    int deg = valid ? min(degp[node], CAP) : 0;
    int r0 = node * CAP;
    // wave-uniform min/max degree over the wave's 4 groups
    int dmin = min(min(__shfl(deg, 0), __shfl(deg, 16)),
                   min(__shfl(deg, 32), __shfl(deg, 48)));
    int dmax = max(max(__shfl(deg, 0), __shfl(deg, 16)),
                   max(__shfl(deg, 32), __shfl(deg, 48)));

    float a0 = 0.f, a1 = 0.f, a2 = 0.f, a3 = 0.f, l = 0.f;

    auto edge_body = [&](int pe, uint2 rw, bool gated, int idx) {
        int rr = pe & 63;
        uint4 uv = *(const uint4*)(sUV + rr * 136 + s * 8);
        float U0 = b2f_lo(uv.x), U1 = b2f_hi(uv.x);
        float U2 = b2f_lo(uv.y), U3 = b2f_hi(uv.y);
        float V0 = b2f_lo(uv.z), V1 = b2f_hi(uv.z);
        float V2 = b2f_lo(uv.w), V3 = b2f_hi(uv.w);
        float e0 = b2f_lo(rw.x), e1 = b2f_hi(rw.x);
        float e2 = b2f_lo(rw.y), e3 = b2f_hi(rw.y);
        float sd = hd0 * U0 + hd1 * U1 + hd2 * U2 + hd3 * U3 +
                   e0 * V0 + e1 * V1 + e2 * V2 + e3 * V3;
        sd = ror_sum16(sd);                   // 64-dot in all 16 lanes
        float p = fmaxf(sd, NEG_SLOPE * sd);  // leaky (slope<1)
        float w = __expf(p);
        if (gated) w = (idx < deg) ? w : 0.f;
        l += w;
        a0 += w * e0; a1 += w * e1; a2 += w * e2; a3 += w * e3;
    };

    int c = 0;
    // fast path: 8 edges/iter, all groups full, no gating
    for (; c + 8 <= dmin; c += 8) {
        uint4 ea = *(const uint4*)(csr + r0 + c);
        uint4 eb = *(const uint4*)(csr + r0 + c + 4);
        int pe[8] = {(int)ea.x, (int)ea.y, (int)ea.z, (int)ea.w,
                     (int)eb.x, (int)eb.y, (int)eb.z, (int)eb.w};
        uint2 rw[8];
#pragma unroll
        for (int u = 0; u < 8; ++u)
            rw[u] = *(const uint2*)(embb + (long)(pe[u] >> 6) * 64 + s * 4);
#pragma unroll
        for (int u = 0; u < 8; ++u) edge_body(pe[u], rw[u], false, 0);
    }
    // gated tail: 4 edges/iter; pe forced 0 before gather (poison safety)
    for (; c < dmax; c += 4) {
        uint4 e4 = *(const uint4*)(csr + r0 + c);
        int pe[4];
        pe[0] = (c + 0 < deg) ? (int)e4.x : 0;
        pe[1] = (c + 1 < deg) ? (int)e4.y : 0;
        pe[2] = (c + 2 < deg) ? (int)e4.z : 0;
        pe[3] = (c + 3 < deg) ? (int)e4.w : 0;
        uint2 rw[4];
#pragma unroll
        for (int u = 0; u < 4; ++u)
            rw[u] = *(const uint2*)(embb + (long)(pe[u] >> 6) * 64 + s * 4);
#pragma unroll
        for (int u = 0; u < 4; ++u) edge_body(pe[u], rw[u], true, c + u);
    }

    if (valid) {
        float inv = (l > 0.f) ? 1.f / l : 0.f;
        float v0 = hd0 + a0 * inv, v1 = hd1 + a1 * inv;
        float v2 = hd2 + a2 * inv, v3 = hd3 + a3 * inv;
        float sq = v0 * v0 + v1 * v1 + v2 * v2 + v3 * v3;
        sq = ror_sum16(sq);                       // group-uniform
        float rn = 1.f / fmaxf(sqrtf(sq), 1e-12f);
        v0 *= rn; v1 *= rn; v2 *= rn; v3 *= rn;
        if (embb_out) {
            ushort4 o = {f2b(v0), f2b(v1), f2b(v2), f2b(v3)};
            *(ushort4*)(embb_out + nb64 + s * 4) = o;
        }
        float4 rp = *(const float4*)(res_prev + nb64 + s * 4);
        float4 ro = {0.5f * rp.x + v0, 0.5f * rp.y + v1,
                     0.5f * rp.z + v2, 0.5f * rp.w + v3};
        *(float4*)(res_out + nb64 + s * 4) = ro;
    }
}

extern "C" void kernel_launch(void* const* d_in, const int* in_sizes, int n_in,
                              void* d_out, int out_size, void* d_ws, size_t ws_size,
                              hipStream_t stream) {
    const int*   edge_index = (const int*)d_in[0];   // [2, E]
    const int*   etype      = (const int*)d_in[1];   // [E]
    const float* ent        = (const float*)d_in[2]; // [N, 64]
    const float* rel        = (const float*)d_in[3]; // [R, 64]
    const float* W          = (const float*)d_in[4]; // [128, 64]

    const int E = in_sizes[1];
    const int N = in_sizes[2] / 64;
    const int R = in_sizes[3] / 64;
    const int* head = edge_index;
    const int* tail = edge_index + E;
    float* out = (float*)d_out;

    const int nbkt = ((N - 1) >> BKT_SHIFT) + 1;  // 196 for N=100000

    // workspace layout
    char* w = (char*)d_ws;
    unsigned short* Wuvb = (unsigned short*)w;  w += (size_t)R * 128 * 2;
    int* gcursor = (int*)w;                     w += 256 * 4;
    int* deg = (int*)w;                         w += ((size_t)N + 64) * 4;
    int* csr = (int*)w;                         w += (size_t)N * CAP * 4;
    uint2* bstream = (uint2*)w;                 w += (size_t)nbkt * BKT_CAP * 8;
    unsigned short* entb = (unsigned short*)w;  w += (size_t)N * 64 * 2;
    unsigned short* emb1b = (unsigned short*)w; w += (size_t)N * 64 * 2;

    const int n4 = N * 16;                      // float4s to cast
    const int ib = R + 1 + (n4 + 255) / 256;
    const int hb = (N + 31) / 32;

    init_kernel<<<ib, 256, 0, stream>>>(W, rel, Wuvb, ent, entb, gcursor,
                                        n4, R, nbkt);

    // two-phase binned CSR build (graph constant across hops)
    binA_kernel<<<512, 256, 0, stream>>>(head, tail, etype, gcursor,
                                         bstream, E, nbkt);
    binB_kernel<<<nbkt, 256, 0, stream>>>(gcursor, bstream, deg, csr, N);

    // hop 1
    hop_kernel<<<hb, 512, 0, stream>>>(deg, csr, Wuvb, entb, ent, emb1b, out, N);
    // hop 2 (res in place)
    hop_kernel<<<hb, 512, 0, stream>>>(deg, csr, Wuvb, emb1b, out, nullptr, out, N);
}

// Round 14
// 264.715 us; speedup vs baseline: 1.1678x; 1.0263x over previous
//
#include <hip/hip_runtime.h>

// ---------------------------------------------------------------------------
// RGAT 2-hop, N=100000, E=1600000, D=64, R=64.
// R14 = R13 + (a) hop logit dot via v_dot2_f32_bf16 (4 instrs replace
// 12 bf16->f32 conversions + 8 FMAs per edge); (b) BKT_SHIFT 9->8:
// 391 buckets of 256 nodes (binB fills 256 CUs; 64KB csr region/bucket).
// Build (R13): phase A partitions edges into bucket streams (LDS hist +
// one global cursor atomic per (block,bucket) + 128B single-writer runs);
// phase B scatters each bucket's contiguous stream into its private csr
// region while L2-hot; deg packed+coalesced from LDS.
// Hop: 16-lane groups, 4 nodes/wave, lane=dim-quad; U,V bf16 ushort8 in
// LDS; DPP row_ror dot-reduce; 8-edge ungated fast path + gated tail.
// ---------------------------------------------------------------------------

#define NEG_SLOPE 0.2f
#define CAP 64
#define BKT_SHIFT 8                  // 256 nodes per bucket
#define BKT_CAP 6144                 // stream slots per bucket (avg ~4096)

__device__ __forceinline__ float b2f_lo(unsigned x) {
    return __uint_as_float(x << 16);
}
__device__ __forceinline__ float b2f_hi(unsigned x) {
    return __uint_as_float(x & 0xffff0000u);
}
__device__ __forceinline__ unsigned short f2b(float x) {  // RNE
    unsigned u = __float_as_uint(x);
    unsigned r = u + 0x7fffu + ((u >> 16) & 1u);
    return (unsigned short)(r >> 16);
}

// D = a.bf16[0]*b.bf16[0] + a.bf16[1]*b.bf16[1] + c   (one VOP3P instr)
__device__ __forceinline__ float dot2bf(unsigned a, unsigned b, float c) {
    float d;
    asm("v_dot2_f32_bf16 %0, %1, %2, %3" : "=v"(d) : "v"(a), "v"(b), "v"(c));
    return d;
}

// sum over the 16 lanes of a row-group; result in ALL 16 lanes. VALU pipe.
__device__ __forceinline__ float ror_sum16(float x) {
#define ROR_ADD(ctrl)                                                          \
    x += __int_as_float(                                                       \
        __builtin_amdgcn_update_dpp(0, __float_as_int(x), ctrl, 0xf, 0xf, true))
    ROR_ADD(0x121);  // row_ror:1
    ROR_ADD(0x122);  // row_ror:2
    ROR_ADD(0x124);  // row_ror:4
    ROR_ADD(0x128);  // row_ror:8
#undef ROR_ADD
    return x;
}

// Fused init: blocks [0,R): Wuv projection; block R: zero bucket cursors;
// rest: cast ent -> bf16.
__global__ __launch_bounds__(256) void init_kernel(
    const float* __restrict__ W, const float* __restrict__ rel,
    unsigned short* __restrict__ Wuvb, const float* __restrict__ ent,
    unsigned short* __restrict__ entb, int* __restrict__ gcursor,
    int n4, int R, int nbkt) {
    if ((int)blockIdx.x < R) {
        int r = blockIdx.x;
        int i = threadIdx.x;  // use 128 of 256
        __shared__ float rels[64];
        if (i < 64) rels[i] = rel[r * 64 + i];
        __syncthreads();
        if (i < 128) {
            float s = 0.f;
#pragma unroll
            for (int j = 0; j < 64; ++j) s += W[i * 64 + j] * rels[j];
            int d = i & 63, half = i >> 6;
            Wuvb[r * 128 + (d >> 2) * 8 + half * 4 + (d & 3)] = f2b(s);
        }
    } else if ((int)blockIdx.x == R) {
        for (int i = threadIdx.x; i < nbkt; i += 256) gcursor[i] = 0;
    } else {
        int i = (blockIdx.x - R - 1) * 256 + threadIdx.x;
        if (i < n4) {
            float4 v = *(const float4*)(ent + (long)i * 4);
            ushort4 o = {f2b(v.x), f2b(v.y), f2b(v.z), f2b(v.w)};
            *(ushort4*)(entb + (long)i * 4) = o;
        }
    }
}

// ---------------- Phase A: partition edges into bucket streams ----------
__global__ __launch_bounds__(256) void binA_kernel(
    const int* __restrict__ head, const int* __restrict__ tail,
    const int* __restrict__ etype, int* __restrict__ gcursor,
    uint2* __restrict__ stream, int E, int nbkt) {
    __shared__ int lcnt[512];
    __shared__ int lbase[512];
    int nb = gridDim.x;
    long e0 = (long)blockIdx.x * E / nb;
    long e1 = (long)(blockIdx.x + 1) * E / nb;
    for (int i = threadIdx.x; i < nbkt; i += 256) lcnt[i] = 0;
    __syncthreads();
    for (long i = e0 + threadIdx.x; i < e1; i += 256)
        atomicAdd(&lcnt[head[i] >> BKT_SHIFT], 1);
    __syncthreads();
    for (int b = threadIdx.x; b < nbkt; b += 256) {
        lbase[b] = atomicAdd(gcursor + b, lcnt[b]);
        lcnt[b] = 0;
    }
    __syncthreads();
    for (long i = e0 + threadIdx.x; i < e1; i += 256) {
        int h = head[i];
        int b = h >> BKT_SHIFT;
        int entry = (tail[i] << 6) | etype[i];
        int p = lbase[b] + atomicAdd(&lcnt[b], 1);
        if (p < BKT_CAP)
            stream[(long)b * BKT_CAP + p] = make_uint2((unsigned)h, (unsigned)entry);
    }
}

// ---------------- Phase B: per-bucket local CSR build -------------------
// One block per bucket; csr region (64 KB) is block-private and L2-hot.
__global__ __launch_bounds__(256) void binB_kernel(
    const int* __restrict__ gcursor, const uint2* __restrict__ stream,
    int* __restrict__ deg, int* __restrict__ csr, int N) {
    __shared__ int cnt[256];
    int b = blockIdx.x;
    cnt[threadIdx.x] = 0;
    __syncthreads();
    int n = min(gcursor[b], BKT_CAP);
    const uint2* sp = stream + (long)b * BKT_CAP;
    for (int i = threadIdx.x; i < n; i += 256) {
        uint2 e = sp[i];
        int c = atomicAdd(&cnt[e.x & 255], 1);
        if (c < CAP) csr[(long)e.x * CAP + c] = (int)e.y;
    }
    __syncthreads();
    int node = (b << BKT_SHIFT) + threadIdx.x;
    if (node < N) deg[node] = cnt[threadIdx.x];
}

// ---------------- fused hop (16-lane groups) ----------------
// 512 threads = 8 waves = 32 nodes per block. Group = 16 lanes = 1 node,
// lane s owns dims 4s..4s+3.
__global__ __launch_bounds__(512) void hop_kernel(
    const int* __restrict__ degp, const int* __restrict__ csr,
    const unsigned short* __restrict__ Wuvb,
    const unsigned short* __restrict__ embb, const float* res_prev,
    unsigned short* embb_out, float* res_out, int N) {
    __shared__ unsigned short sUV[64 * 136];  // 17 KB, skewed stride
    for (int k = threadIdx.x; k < 64 * 128; k += 512) {
        int r = k >> 7, q = k & 127;
        sUV[r * 136 + q] = Wuvb[k];
    }
    __syncthreads();

    int tid = threadIdx.x;
    int s = tid & 15;
    int node = blockIdx.x * 32 + (tid >> 4);
    bool valid = node < N;
    long nb64 = (long)node * 64;

    uint2 hdp = valid ? *(const uint2*)(embb + nb64 + s * 4)
                      : make_uint2(0u, 0u);

    int deg = valid ? min(degp[node], CAP) : 0;
    int r0 = node * CAP;
    // wave-uniform min/max degree over the wave's 4 groups
    int dmin = min(min(__shfl(deg, 0), __shfl(deg, 16)),
                   min(__shfl(deg, 32), __shfl(deg, 48)));
    int dmax = max(max(__shfl(deg, 0), __shfl(deg, 16)),
                   max(__shfl(deg, 32), __shfl(deg, 48)));

    float a0 = 0.f, a1 = 0.f, a2 = 0.f, a3 = 0.f, l = 0.f;

    auto edge_body = [&](int pe, uint2 rw, bool gated, int idx) {
        int rr = pe & 63;
        uint4 uv = *(const uint4*)(sUV + rr * 136 + s * 8);
        float sd = dot2bf(hdp.x, uv.x, 0.f);   // hd01 . U01
        sd = dot2bf(hdp.y, uv.y, sd);          // hd23 . U23
        sd = dot2bf(rw.x, uv.z, sd);           // row01 . V01
        sd = dot2bf(rw.y, uv.w, sd);           // row23 . V23
        sd = ror_sum16(sd);                    // 64-dot in all 16 lanes
        float p = fmaxf(sd, NEG_SLOPE * sd);   // leaky (slope<1)
        float w = __expf(p);
        if (gated) w = (idx < deg) ? w : 0.f;
        l += w;
        float e0 = b2f_lo(rw.x), e1 = b2f_hi(rw.x);
        float e2 = b2f_lo(rw.y), e3 = b2f_hi(rw.y);
        a0 += w * e0; a1 += w * e1; a2 += w * e2; a3 += w * e3;
    };

    int c = 0;
    // fast path: 8 edges/iter, all groups full, no gating
    for (; c + 8 <= dmin; c += 8) {
        uint4 ea = *(const uint4*)(csr + r0 + c);
        uint4 eb = *(const uint4*)(csr + r0 + c + 4);
        int pe[8] = {(int)ea.x, (int)ea.y, (int)ea.z, (int)ea.w,
                     (int)eb.x, (int)eb.y, (int)eb.z, (int)eb.w};
        uint2 rw[8];
#pragma unroll
        for (int u = 0; u < 8; ++u)
            rw[u] = *(const uint2*)(embb + (long)(pe[u] >> 6) * 64 + s * 4);
#pragma unroll
        for (int u = 0; u < 8; ++u) edge_body(pe[u], rw[u], false, 0);
    }
    // gated tail: 4 edges/iter; pe forced 0 before gather (poison safety)
    for (; c < dmax; c += 4) {
        uint4 e4 = *(const uint4*)(csr + r0 + c);
        int pe[4];
        pe[0] = (c + 0 < deg) ? (int)e4.x : 0;
        pe[1] = (c + 1 < deg) ? (int)e4.y : 0;
        pe[2] = (c + 2 < deg) ? (int)e4.z : 0;
        pe[3] = (c + 3 < deg) ? (int)e4.w : 0;
        uint2 rw[4];
#pragma unroll
        for (int u = 0; u < 4; ++u)
            rw[u] = *(const uint2*)(embb + (long)(pe[u] >> 6) * 64 + s * 4);
#pragma unroll
        for (int u = 0; u < 4; ++u) edge_body(pe[u], rw[u], true, c + u);
    }

    if (valid) {
        float hd0 = b2f_lo(hdp.x), hd1 = b2f_hi(hdp.x);
        float hd2 = b2f_lo(hdp.y), hd3 = b2f_hi(hdp.y);
        float inv = (l > 0.f) ? 1.f / l : 0.f;
        float v0 = hd0 + a0 * inv, v1 = hd1 + a1 * inv;
        float v2 = hd2 + a2 * inv, v3 = hd3 + a3 * inv;
        float sq = v0 * v0 + v1 * v1 + v2 * v2 + v3 * v3;
        sq = ror_sum16(sq);                       // group-uniform
        float rn = 1.f / fmaxf(sqrtf(sq), 1e-12f);
        v0 *= rn; v1 *= rn; v2 *= rn; v3 *= rn;
        if (embb_out) {
            ushort4 o = {f2b(v0), f2b(v1), f2b(v2), f2b(v3)};
            *(ushort4*)(embb_out + nb64 + s * 4) = o;
        }
        float4 rp = *(const float4*)(res_prev + nb64 + s * 4);
        float4 ro = {0.5f * rp.x + v0, 0.5f * rp.y + v1,
                     0.5f * rp.z + v2, 0.5f * rp.w + v3};
        *(float4*)(res_out + nb64 + s * 4) = ro;
    }
}

extern "C" void kernel_launch(void* const* d_in, const int* in_sizes, int n_in,
                              void* d_out, int out_size, void* d_ws, size_t ws_size,
                              hipStream_t stream) {
    const int*   edge_index = (const int*)d_in[0];   // [2, E]
    const int*   etype      = (const int*)d_in[1];   // [E]
    const float* ent        = (const float*)d_in[2]; // [N, 64]
    const float* rel        = (const float*)d_in[3]; // [R, 64]
    const float* W          = (const float*)d_in[4]; // [128, 64]

    const int E = in_sizes[1];
    const int N = in_sizes[2] / 64;
    const int R = in_sizes[3] / 64;
    const int* head = edge_index;
    const int* tail = edge_index + E;
    float* out = (float*)d_out;

    const int nbkt = ((N - 1) >> BKT_SHIFT) + 1;  // 391 for N=100000

    // workspace layout
    char* w = (char*)d_ws;
    unsigned short* Wuvb = (unsigned short*)w;  w += (size_t)R * 128 * 2;
    int* gcursor = (int*)w;                     w += 512 * 4;
    int* deg = (int*)w;                         w += ((size_t)N + 64) * 4;
    int* csr = (int*)w;                         w += (size_t)N * CAP * 4;
    uint2* bstream = (uint2*)w;                 w += (size_t)nbkt * BKT_CAP * 8;
    unsigned short* entb = (unsigned short*)w;  w += (size_t)N * 64 * 2;
    unsigned short* emb1b = (unsigned short*)w; w += (size_t)N * 64 * 2;

    const int n4 = N * 16;                      // float4s to cast
    const int ib = R + 1 + (n4 + 255) / 256;
    const int hb = (N + 31) / 32;

    init_kernel<<<ib, 256, 0, stream>>>(W, rel, Wuvb, ent, entb, gcursor,
                                        n4, R, nbkt);

    // two-phase binned CSR build (graph constant across hops)
    binA_kernel<<<512, 256, 0, stream>>>(head, tail, etype, gcursor,
                                         bstream, E, nbkt);
    binB_kernel<<<nbkt, 256, 0, stream>>>(gcursor, bstream, deg, csr, N);

    // hop 1
    hop_kernel<<<hb, 512, 0, stream>>>(deg, csr, Wuvb, entb, ent, emb1b, out, N);
    // hop 2 (res in place)
    hop_kernel<<<hb, 512, 0, stream>>>(deg, csr, Wuvb, emb1b, out, nullptr, out, N);
}